// Round 12
// baseline (236.862 us; speedup 1.0000x reference)
//
#include <hip/hip_runtime.h>
#include <hip/hip_fp16.h>

typedef _Float16 f16;
typedef _Float16 f16x8 __attribute__((ext_vector_type(8)));
typedef _Float16 f16x4 __attribute__((ext_vector_type(4)));
typedef float f32x4 __attribute__((ext_vector_type(4)));
typedef float f32x16 __attribute__((ext_vector_type(16)));

#define GLB(p) ((const __attribute__((address_space(1))) void*)(p))
#define LDSP(p) ((__attribute__((address_space(3))) void*)(p))

__device__ __forceinline__ void gload16(const void* g, void* l) {
  __builtin_amdgcn_global_load_lds(GLB(g), LDSP(l), 16, 0, 0);
}

#define VMW(n) asm volatile("s_waitcnt vmcnt(" #n ")" ::: "memory")
__device__ __forceinline__ void barrier_fenced() {
  asm volatile("" ::: "memory");
  __builtin_amdgcn_s_barrier();
  asm volatile("" ::: "memory");
}

// ---------------- xpose: x -> xb (f16 [t][c]) + xbT (f16 [bc][c][t]) ----------------
// 512 blocks = 64 bc x 8 tt; tile [32 t][256 c]; LDS transpose, 8B writes.
__global__ __launch_bounds__(256) void xpose(const float* __restrict__ x,
                                             f16* __restrict__ xb,
                                             f16* __restrict__ xbT) {
  __shared__ f16 t[32 * 268];
  const int tid = threadIdx.x;
  const int bc = blockIdx.x >> 3, tt = blockIdx.x & 7;
  const long tbase = (long)(bc * 256 + tt * 32);
#pragma unroll
  for (int i = 0; i < 8; ++i) {
    int tr = (tid >> 6) + i * 4;  // 0..31
    int c4 = (tid & 63) * 4;
    float4 v = *(const float4*)(x + (tbase + tr) * 256 + c4);
    f16x4 o = {(f16)v.x, (f16)v.y, (f16)v.z, (f16)v.w};
    *(f16x4*)(xb + (tbase + tr) * 256 + c4) = o;
    *(f16x4*)(&t[tr * 268 + c4]) = o;
  }
  __syncthreads();
#pragma unroll
  for (int i = 0; i < 8; ++i) {
    int c = (tid >> 3) + i * 32;  // 0..255
    int t0 = (tid & 7) * 4;       // 0..28
    f16x4 v;
#pragma unroll
    for (int j = 0; j < 4; ++j) v[j] = t[(t0 + j) * 268 + c];
    *(f16x4*)(&xbT[(long)bc * 65536 + (long)c * 256 + tt * 32 + t0]) = v;
  }
}

// ---------------- prep_w2: per-head K-innermost weights + permuted biases ----------
// WqT2/WkT2/WvT2[h*256+c][d] = W[c][d*8+h]; WoT[dm][h*256+d] = Wo[(d*8+h)][dm]
__global__ __launch_bounds__(256) void prep_w2(
    const float* __restrict__ Wq, const float* __restrict__ Wk,
    const float* __restrict__ Wv, const float* __restrict__ Wo,
    const float* __restrict__ bq, const float* __restrict__ bv,
    f16* __restrict__ WqT2, f16* __restrict__ WkT2, f16* __restrict__ WvT2,
    f16* __restrict__ WoT, float* __restrict__ bqp, float* __restrict__ bvp) {
  int g = blockIdx.x * 256 + threadIdx.x;  // 0..524287
  int hc = g >> 8, d = g & 255;
  int h = hc >> 8, c = hc & 255;
  int src = c * 2048 + d * 8 + h;
  WqT2[g] = (f16)Wq[src];
  WkT2[g] = (f16)Wk[src];
  WvT2[g] = (f16)Wv[src];
  int dm = g >> 11, np = g & 2047;
  WoT[g] = (f16)Wo[((np & 255) * 8 + (np >> 8)) * 256 + dm];
  if (g < 2048) {
    int s2 = (g & 255) * 8 + (g >> 8);
    bqp[g] = bq[s2];
    bvp[g] = bv[s2];
  }
}

// ---------------- gemm_pre: MT_h, GT_h (128x256 tiles, K=256) + wv + bo2 ----------
__global__ __launch_bounds__(256) void gemm_pre(
    const f16* __restrict__ WqT2, const f16* __restrict__ WkT2,
    const f16* __restrict__ WvT2, const f16* __restrict__ WoT,
    const float* __restrict__ bqp, const float* __restrict__ bvp,
    const float* __restrict__ bo, f16* __restrict__ MT, f16* __restrict__ GT,
    float* __restrict__ wv, float* __restrict__ bo2) {
  const int bid = blockIdx.x;
  if (bid >= 32) {
    if (bid == 32) {
      int c = threadIdx.x;
      for (int h = 0; h < 8; ++h) {
        const f16* row = WkT2 + ((h * 256 + c) << 8);
        float acc = 0.f;
        for (int d8 = 0; d8 < 32; ++d8) {
          f16x8 kv = *(const f16x8*)(row + d8 * 8);
#pragma unroll
          for (int e = 0; e < 8; ++e)
            acc += (float)kv[e] * bqp[h * 256 + d8 * 8 + e];
        }
        wv[h * 256 + c] = acc;
      }
    } else {
      int dm = threadIdx.x;
      const f16* row = WoT + dm * 2048;
      float acc = bo[dm];
      for (int n8 = 0; n8 < 256; ++n8) {
        f16x8 ov = *(const f16x8*)(row + n8 * 8);
#pragma unroll
        for (int e = 0; e < 8; ++e) acc += (float)ov[e] * bvp[n8 * 8 + e];
      }
      bo2[dm] = acc;
    }
    return;
  }
  __shared__ __align__(16) char smem[49152];  // A 2x8KB @0, B 2x16KB @16384
  const int mat = bid >> 4, h = (bid >> 1) & 7, mt = bid & 1;
  const f16* A;
  long As;
  const f16* B;
  f16* C;
  if (mat == 0) {
    A = WkT2 + h * 65536 + mt * 32768;
    As = 256;
    B = WqT2 + h * 65536;
    C = MT + h * 65536 + mt * 32768;
  } else {
    A = WoT + h * 256 + (long)mt * 128 * 2048;
    As = 2048;
    B = WvT2 + h * 65536;
    C = GT + h * 65536 + mt * 32768;
  }
  const int tid = threadIdx.x;
  const int lane = tid & 63, wid = tid >> 6;  // 4 waves
  const int l15 = lane & 15, lg = lane >> 4;
  const int w32 = wid * 32;

  auto stageA = [&](int ct) {
#pragma unroll
    for (int r = 0; r < 2; ++r) {
      int flat = r * 4096 + tid * 16;
      int row = flat >> 6;
      int kk = ct * 32 + (((flat ^ (((row >> 1) & 3) << 4)) & 63) >> 1);
      gload16(A + (long)row * As + kk, smem + (ct & 1) * 8192 + flat);
    }
  };
  auto stageB = [&](int ct) {
#pragma unroll
    for (int r = 0; r < 4; ++r) {
      int flat = r * 4096 + tid * 16;
      int row = flat >> 6;
      int kk = ct * 32 + (((flat ^ (((row >> 1) & 3) << 4)) & 63) >> 1);
      gload16(B + (long)row * 256 + kk, smem + 16384 + (ct & 1) * 16384 + flat);
    }
  };
  auto ldA = [&](int ct, int row) -> f16x8 {
    return *(const f16x8*)(smem + (ct & 1) * 8192 + row * 64 +
                           ((lg * 16) ^ (((row >> 1) & 3) << 4)));
  };
  auto ldB = [&](int ct, int row) -> f16x8 {
    return *(const f16x8*)(smem + 16384 + (ct & 1) * 16384 + row * 64 +
                           ((lg * 16) ^ (((row >> 1) & 3) << 4)));
  };

  f32x4 acc[2][16] = {};
  stageA(0);
  stageB(0);
  for (int ct = 0; ct < 8; ++ct) {
    VMW(0);
    barrier_fenced();
    if (ct < 7) {
      stageA(ct + 1);
      stageB(ct + 1);
    }
    f16x8 af[2];
#pragma unroll
    for (int i = 0; i < 2; ++i) af[i] = ldA(ct, w32 + i * 16 + l15);
#pragma unroll
    for (int f = 0; f < 16; ++f) {
      f16x8 bf = ldB(ct, f * 16 + l15);
#pragma unroll
      for (int i = 0; i < 2; ++i)
        acc[i][f] = __builtin_amdgcn_mfma_f32_16x16x32_f16(af[i], bf, acc[i][f], 0, 0, 0);
    }
  }
#pragma unroll
  for (int i = 0; i < 2; ++i)
#pragma unroll
    for (int f = 0; f < 16; ++f)
#pragma unroll
      for (int jj = 0; jj < 4; ++jj)
        C[(w32 + i * 16 + lg * 4 + jj) * 256 + f * 16 + l15] = (f16)acc[i][f][jj];
}

// ---------------- vcomp: v[bc][h][j] = sum_c xb[bc][j][c] * wv[h][c] ----------------
__global__ __launch_bounds__(256) void vcomp(const f16* __restrict__ xb,
                                             const float* __restrict__ wv,
                                             float* __restrict__ v) {
  __shared__ float wl[2048];
  const int bc = blockIdx.x, tid = threadIdx.x;
  for (int r = 0; r < 8; ++r) wl[r * 256 + tid] = wv[r * 256 + tid];
  __syncthreads();
  const f16* row = xb + (long)bc * 65536 + (long)tid * 256;
  float a[8] = {};
  for (int c8 = 0; c8 < 32; ++c8) {
    f16x8 xv = *(const f16x8*)(row + c8 * 8);
#pragma unroll
    for (int h = 0; h < 8; ++h) {
      float s = 0.f;
#pragma unroll
      for (int e = 0; e < 8; ++e) s += (float)xv[e] * wl[h * 256 + c8 * 8 + e];
      a[h] += s;
    }
  }
  for (int h = 0; h < 8; ++h) v[bc * 2048 + h * 256 + tid] = a[h];
}

// ---------------- attn_fused7: 256-row blocks, 32x32x16 MFMA, continuous pipeline ----
// Block (bc, h): 256 q rows; 8 waves x 32 wave-private rows.
// One 64-step B-stream: phases T(MT) S(xB) R(xT) Z(GT), each 16 steps of
// [128 n][32 k] 8KB tiles through 4 rotating bufs, counted VMW(2) throughout.
// region0 @0: [256][256] f16 (xA staged -> T -> P -> R), swizzle
//   byte = row*512 + (col*2 ^ ((row&7)<<4)); rows wave-private: no barriers.
// B bufs @131072: 4 x 8KB. LDS = 160 KB exactly -> 1 block/CU.
__global__ __launch_bounds__(512, 2) void attn_fused7(
    const f16* __restrict__ xb, const f16* __restrict__ xbT,
    const f16* __restrict__ MT, const f16* __restrict__ GT,
    const float* __restrict__ vw, f16* __restrict__ Zp) {
  __shared__ __align__(16) char smem[163840];
  const int tid = threadIdx.x;
  const int lane = tid & 63, wid = tid >> 6;  // 8 waves
  const int l31 = lane & 31, lh = lane >> 5;
  const int w32 = wid * 32;
  const int bc = blockIdx.x, h = blockIdx.y;
  const f16* xB = xb + (long)bc * 65536;   // [t][c] (also the phase-T A source)
  const f16* xT = xbT + (long)bc * 65536;  // [c][t]
  const f16* MTh = MT + h * 65536;         // [c'][c]
  const f16* GTh = GT + h * 65536;         // [dm][c]

  float vv[8];
  {
    const float* vb = vw + bc * 2048 + h * 256;
#pragma unroll
    for (int idx = 0; idx < 8; ++idx)
      vv[idx] = vb[(idx >> 2) * 128 + (idx & 3) * 32 + l31];
  }

  // stage full xA (=x_bc, 128KB) into region0 (linear dest, pre-swizzled src)
  auto stageX = [&]() {
#pragma unroll
    for (int i = 0; i < 16; ++i) {
      int flat = i * 8192 + tid * 16;
      int row = flat >> 9;
      int colb = (flat & 511) ^ ((row & 7) << 4);
      gload16(xB + (long)row * 256 + (colb >> 1), smem + flat);
    }
  };
  // stage B tile for global step g: 8KB, 1 load/thread
  auto stageBg = [&](int g) {
    const f16* src = g < 16 ? MTh : g < 32 ? xB : g < 48 ? xT : GTh;
    int s = g & 15, kt = s >> 1, hf = s & 1;
    int flat = tid * 16;
    int row = flat >> 6;  // 0..127
    int colb = (flat & 63) ^ (((row >> 1) & 3) << 4);
    gload16(src + (long)(hf * 128 + row) * 256 + kt * 32 + (colb >> 1),
            smem + 131072 + (g & 3) * 8192 + flat);
  };
  auto ldA = [&](int kt, int kf) -> f16x8 {
    int row = w32 + l31;
    return *(const f16x8*)(smem + row * 512 +
                           ((kt * 64 + kf * 32 + lh * 16) ^ ((row & 7) << 4)));
  };
  auto ldB = [&](int g, int nt, int kf) -> f16x8 {
    int row = nt * 32 + l31;
    return *(const f16x8*)(smem + 131072 + (g & 3) * 8192 + row * 64 +
                           ((kf * 32 + lh * 16) ^ (((row >> 1) & 3) << 4)));
  };
  auto st0 = [&](int row, int col, f16 v_) {
    *(f16*)(smem + row * 512 + ((col * 2) ^ ((row & 7) << 4))) = v_;
  };

  f32x16 acc[8];
  auto zacc = [&]() {
#pragma unroll
    for (int i = 0; i < 8; ++i) acc[i] = (f32x16)(0.f);
  };
  // one pipeline step; acc[hf*4+nt] over nt 0..3, kf 0..1 (g,kt,hf compile-time)
  auto step = [&](int g, int kt, int hf) {
    if (g < 62) {
      VMW(2);
    } else if (g == 62) {
      VMW(1);
    } else {
      VMW(0);
    }
    barrier_fenced();
    if (g + 3 < 64) stageBg(g + 3);
    f16x8 a0 = ldA(kt, 0), a1 = ldA(kt, 1);
    __builtin_amdgcn_s_setprio(1);
#pragma unroll
    for (int nt = 0; nt < 4; ++nt) {
      f16x8 b0 = ldB(g, nt, 0);
      acc[hf * 4 + nt] =
          __builtin_amdgcn_mfma_f32_32x32x16_f16(a0, b0, acc[hf * 4 + nt], 0, 0, 0);
      f16x8 b1 = ldB(g, nt, 1);
      acc[hf * 4 + nt] =
          __builtin_amdgcn_mfma_f32_32x32x16_f16(a1, b1, acc[hf * 4 + nt], 0, 0, 0);
    }
    __builtin_amdgcn_s_setprio(0);
  };
  // write acc to region0 (own rows; C layout row=(r&3)+8*(r>>2)+4*lh, col=lane&31)
  auto wr0 = [&]() {
#pragma unroll
    for (int idx = 0; idx < 8; ++idx)
#pragma unroll
      for (int r = 0; r < 16; ++r)
        st0(w32 + (r & 3) + 8 * (r >> 2) + 4 * lh,
            (idx >> 2) * 128 + (idx & 3) * 32 + l31, (f16)acc[idx][r]);
  };

  // prologue: xA + 3 B tiles in flight
  stageX();
  stageBg(0);
  stageBg(1);
  stageBg(2);

  // ---- phase T: T = xA * MT^T ----
  zacc();
#pragma unroll
  for (int s = 0; s < 16; ++s) step(s, s >> 1, s & 1);
  wr0();

  // ---- phase S: S = T * xB^T ----
  zacc();
#pragma unroll
  for (int s = 0; s < 16; ++s) step(16 + s, s >> 1, s & 1);

  // softmax over 256 j per row (rows wave-private; 32-lane groups per lh)
  {
    const float SCL = 0.0625f * 1.44269504089f;
#pragma unroll
    for (int r = 0; r < 16; ++r) {
      float m_ = acc[0][r] + vv[0];
#pragma unroll
      for (int idx = 1; idx < 8; ++idx) m_ = fmaxf(m_, acc[idx][r] + vv[idx]);
#pragma unroll
      for (int off = 1; off < 32; off <<= 1) m_ = fmaxf(m_, __shfl_xor(m_, off, 64));
      float s_ = 0.f;
#pragma unroll
      for (int idx = 0; idx < 8; ++idx) {
        float e = __builtin_exp2f((acc[idx][r] + vv[idx] - m_) * SCL);
        acc[idx][r] = e;
        s_ += e;
      }
#pragma unroll
      for (int off = 1; off < 32; off <<= 1) s_ += __shfl_xor(s_, off, 64);
      float inv = 1.f / s_;
#pragma unroll
      for (int idx = 0; idx < 8; ++idx) acc[idx][r] *= inv;
    }
  }
  wr0();  // P -> region0

  // ---- phase R: R = P * x (B = xT) ----
  zacc();
#pragma unroll
  for (int s = 0; s < 16; ++s) step(32 + s, s >> 1, s & 1);
  wr0();  // R -> region0

  // ---- phase Z: Z = R * G^T (B = GT) ----
  zacc();
#pragma unroll
  for (int s = 0; s < 16; ++s) step(48 + s, s >> 1, s & 1);

  // write Z partial: Zp[bc][t][h*256+dm]
  const long zb = (long)bc * 524288 + h * 256;
#pragma unroll
  for (int idx = 0; idx < 8; ++idx)
#pragma unroll
    for (int r = 0; r < 16; ++r) {
      int trow = w32 + (r & 3) + 8 * (r >> 2) + 4 * lh;
      int dm = (idx >> 2) * 128 + (idx & 3) * 32 + l31;
      Zp[zb + (long)trow * 2048 + dm] = (f16)acc[idx][r];
    }
}

// ---------------- reduce2: out = sum_h Zp + bo2 ----------------
__global__ __launch_bounds__(256) void reduce2(const f16* __restrict__ Zp,
                                               const float* __restrict__ bo2,
                                               float* __restrict__ out) {
  int g = blockIdx.x * 256 + threadIdx.x;  // 4096 blocks
  int flat = g * 4;                        // 4,194,304 f32 output
  int dm = flat & 255;
  int t = (flat >> 8) & 255;
  int bc = flat >> 16;  // 0..63
  const f16* zp = Zp + (long)bc * 524288 + (long)t * 2048 + dm;
  float4 s = *(const float4*)(bo2 + dm);
#pragma unroll
  for (int h = 0; h < 8; ++h) {
    f16x4 zv = *(const f16x4*)(zp + h * 256);
    s.x += (float)zv[0];
    s.y += (float)zv[1];
    s.z += (float)zv[2];
    s.w += (float)zv[3];
  }
  *(float4*)(out + flat) = s;
}

// ---------------- launch ----------------
// ws layout (bytes):
//   xb    @ 0         8388608    f16 [16384 tok][256 c]
//   xbT   @ 8388608   8388608    f16 [bc][256 c][256 t]
//   WqT2  @ 16777216  1048576    f16 [h*256+c][256 d]
//   WkT2  @ 17825792  1048576
//   WvT2  @ 18874368  1048576
//   WoT   @ 19922944  1048576    f16 [dm][h*256+d]
//   bqp   @ 20971520  8192       f32 [h*256+d]
//   bvp   @ 20979712  8192
//   MT    @ 20987904  1048576    f16 [h][c'][c]
//   GT    @ 22036480  1048576    f16 [h][dm][c]
//   wv    @ 23085056  8192       f32 [h][c]
//   bo2   @ 23093248  1024       f32 [dm]
//   v     @ 23094272  524288     f32 [bc][h][j]
//   Zp    @ 23618560  67108864   f16 [bc][t][h*256+dm]
extern "C" void kernel_launch(void* const* d_in, const int* in_sizes, int n_in,
                              void* d_out, int out_size, void* d_ws,
                              size_t ws_size, hipStream_t stream) {
  const float* x = (const float*)d_in[0];
  const float* Wq = (const float*)d_in[1];
  const float* bq = (const float*)d_in[2];
  const float* Wk = (const float*)d_in[3];
  const float* Wv = (const float*)d_in[5];
  const float* bv = (const float*)d_in[6];
  const float* Wo = (const float*)d_in[7];
  const float* bo = (const float*)d_in[8];

  char* ws = (char*)d_ws;
  f16* xb = (f16*)(ws + 0);
  f16* xbT = (f16*)(ws + 8388608);
  f16* WqT2 = (f16*)(ws + 16777216);
  f16* WkT2 = (f16*)(ws + 17825792);
  f16* WvT2 = (f16*)(ws + 18874368);
  f16* WoT = (f16*)(ws + 19922944);
  float* bqp = (float*)(ws + 20971520);
  float* bvp = (float*)(ws + 20979712);
  f16* MTws = (f16*)(ws + 20987904);
  f16* GTws = (f16*)(ws + 22036480);
  float* wvv = (float*)(ws + 23085056);
  float* bo2 = (float*)(ws + 23093248);
  float* vws = (float*)(ws + 23094272);
  f16* Zp = (f16*)(ws + 23618560);
  if (ws_size < 23618560ull + 67108864ull) return;  // ~87MB

  xpose<<<512, 256, 0, stream>>>(x, xb, xbT);
  prep_w2<<<2048, 256, 0, stream>>>(Wq, Wk, Wv, Wo, bq, bv, WqT2, WkT2, WvT2,
                                    WoT, bqp, bvp);
  gemm_pre<<<34, 256, 0, stream>>>(WqT2, WkT2, WvT2, WoT, bqp, bvp, bo, MTws,
                                   GTws, wvv, bo2);
  vcomp<<<64, 256, 0, stream>>>(xb, wvv, vws);
  // grid (bc, h): id = h*64+bc -> id%8 = bc%8: all 8 h-blocks of a bc on one XCD
  attn_fused7<<<dim3(64, 8), 512, 0, stream>>>(xb, xbT, MTws, GTws, vws, Zp);
  reduce2<<<4096, 256, 0, stream>>>(Zp, bo2, (float*)d_out);
}

// Round 13
// 233.390 us; speedup vs baseline: 1.0149x; 1.0149x over previous
//
#include <hip/hip_runtime.h>
#include <hip/hip_fp16.h>

typedef _Float16 f16;
typedef _Float16 f16x8 __attribute__((ext_vector_type(8)));
typedef _Float16 f16x4 __attribute__((ext_vector_type(4)));
typedef float f32x4 __attribute__((ext_vector_type(4)));
typedef float f32x16 __attribute__((ext_vector_type(16)));

#define GLB(p) ((const __attribute__((address_space(1))) void*)(p))
#define LDSP(p) ((__attribute__((address_space(3))) void*)(p))

__device__ __forceinline__ void gload16(const void* g, void* l) {
  __builtin_amdgcn_global_load_lds(GLB(g), LDSP(l), 16, 0, 0);
}

#define VMW(n) asm volatile("s_waitcnt vmcnt(" #n ")" ::: "memory")
__device__ __forceinline__ void barrier_fenced() {
  asm volatile("" ::: "memory");
  __builtin_amdgcn_s_barrier();
  asm volatile("" ::: "memory");
}

// ---------------- xpose: x -> xb (f16 [t][c]) + xbT (f16 [bc][c][t]) ----------------
// 512 blocks = 64 bc x 8 tt; tile [32 t][256 c]; LDS transpose, 8B writes.
__global__ __launch_bounds__(256) void xpose(const float* __restrict__ x,
                                             f16* __restrict__ xb,
                                             f16* __restrict__ xbT) {
  __shared__ f16 t[32 * 268];
  const int tid = threadIdx.x;
  const int bc = blockIdx.x >> 3, tt = blockIdx.x & 7;
  const long tbase = (long)(bc * 256 + tt * 32);
#pragma unroll
  for (int i = 0; i < 8; ++i) {
    int tr = (tid >> 6) + i * 4;  // 0..31
    int c4 = (tid & 63) * 4;
    float4 v = *(const float4*)(x + (tbase + tr) * 256 + c4);
    f16x4 o = {(f16)v.x, (f16)v.y, (f16)v.z, (f16)v.w};
    *(f16x4*)(xb + (tbase + tr) * 256 + c4) = o;
    *(f16x4*)(&t[tr * 268 + c4]) = o;
  }
  __syncthreads();
#pragma unroll
  for (int i = 0; i < 8; ++i) {
    int c = (tid >> 3) + i * 32;  // 0..255
    int t0 = (tid & 7) * 4;       // 0..28
    f16x4 v;
#pragma unroll
    for (int j = 0; j < 4; ++j) v[j] = t[(t0 + j) * 268 + c];
    *(f16x4*)(&xbT[(long)bc * 65536 + (long)c * 256 + tt * 32 + t0]) = v;
  }
}

// ---------------- prep_w2: per-head K-innermost weights + permuted biases ----------
// WqT2/WkT2/WvT2[h*256+c][d] = W[c][d*8+h]; WoT[dm][h*256+d] = Wo[(d*8+h)][dm]
__global__ __launch_bounds__(256) void prep_w2(
    const float* __restrict__ Wq, const float* __restrict__ Wk,
    const float* __restrict__ Wv, const float* __restrict__ Wo,
    const float* __restrict__ bq, const float* __restrict__ bv,
    f16* __restrict__ WqT2, f16* __restrict__ WkT2, f16* __restrict__ WvT2,
    f16* __restrict__ WoT, float* __restrict__ bqp, float* __restrict__ bvp) {
  int g = blockIdx.x * 256 + threadIdx.x;  // 0..524287
  int hc = g >> 8, d = g & 255;
  int h = hc >> 8, c = hc & 255;
  int src = c * 2048 + d * 8 + h;
  WqT2[g] = (f16)Wq[src];
  WkT2[g] = (f16)Wk[src];
  WvT2[g] = (f16)Wv[src];
  int dm = g >> 11, np = g & 2047;
  WoT[g] = (f16)Wo[((np & 255) * 8 + (np >> 8)) * 256 + dm];
  if (g < 2048) {
    int s2 = (g & 255) * 8 + (g >> 8);
    bqp[g] = bq[s2];
    bvp[g] = bv[s2];
  }
}

// ---------------- gemm_pre: MT_h, GT_h (128x256 tiles, K=256) + wv + bo2 ----------
__global__ __launch_bounds__(256) void gemm_pre(
    const f16* __restrict__ WqT2, const f16* __restrict__ WkT2,
    const f16* __restrict__ WvT2, const f16* __restrict__ WoT,
    const float* __restrict__ bqp, const float* __restrict__ bvp,
    const float* __restrict__ bo, f16* __restrict__ MT, f16* __restrict__ GT,
    float* __restrict__ wv, float* __restrict__ bo2) {
  const int bid = blockIdx.x;
  if (bid >= 32) {
    if (bid == 32) {
      int c = threadIdx.x;
      for (int h = 0; h < 8; ++h) {
        const f16* row = WkT2 + ((h * 256 + c) << 8);
        float acc = 0.f;
        for (int d8 = 0; d8 < 32; ++d8) {
          f16x8 kv = *(const f16x8*)(row + d8 * 8);
#pragma unroll
          for (int e = 0; e < 8; ++e)
            acc += (float)kv[e] * bqp[h * 256 + d8 * 8 + e];
        }
        wv[h * 256 + c] = acc;
      }
    } else {
      int dm = threadIdx.x;
      const f16* row = WoT + dm * 2048;
      float acc = bo[dm];
      for (int n8 = 0; n8 < 256; ++n8) {
        f16x8 ov = *(const f16x8*)(row + n8 * 8);
#pragma unroll
        for (int e = 0; e < 8; ++e) acc += (float)ov[e] * bvp[n8 * 8 + e];
      }
      bo2[dm] = acc;
    }
    return;
  }
  __shared__ __align__(16) char smem[49152];  // A 2x8KB @0, B 2x16KB @16384
  const int mat = bid >> 4, h = (bid >> 1) & 7, mt = bid & 1;
  const f16* A;
  long As;
  const f16* B;
  f16* C;
  if (mat == 0) {
    A = WkT2 + h * 65536 + mt * 32768;
    As = 256;
    B = WqT2 + h * 65536;
    C = MT + h * 65536 + mt * 32768;
  } else {
    A = WoT + h * 256 + (long)mt * 128 * 2048;
    As = 2048;
    B = WvT2 + h * 65536;
    C = GT + h * 65536 + mt * 32768;
  }
  const int tid = threadIdx.x;
  const int lane = tid & 63, wid = tid >> 6;  // 4 waves
  const int l15 = lane & 15, lg = lane >> 4;
  const int w32 = wid * 32;

  auto stageA = [&](int ct) {
#pragma unroll
    for (int r = 0; r < 2; ++r) {
      int flat = r * 4096 + tid * 16;
      int row = flat >> 6;
      int kk = ct * 32 + (((flat ^ (((row >> 1) & 3) << 4)) & 63) >> 1);
      gload16(A + (long)row * As + kk, smem + (ct & 1) * 8192 + flat);
    }
  };
  auto stageB = [&](int ct) {
#pragma unroll
    for (int r = 0; r < 4; ++r) {
      int flat = r * 4096 + tid * 16;
      int row = flat >> 6;
      int kk = ct * 32 + (((flat ^ (((row >> 1) & 3) << 4)) & 63) >> 1);
      gload16(B + (long)row * 256 + kk, smem + 16384 + (ct & 1) * 16384 + flat);
    }
  };
  auto ldA = [&](int ct, int row) -> f16x8 {
    return *(const f16x8*)(smem + (ct & 1) * 8192 + row * 64 +
                           ((lg * 16) ^ (((row >> 1) & 3) << 4)));
  };
  auto ldB = [&](int ct, int row) -> f16x8 {
    return *(const f16x8*)(smem + 16384 + (ct & 1) * 16384 + row * 64 +
                           ((lg * 16) ^ (((row >> 1) & 3) << 4)));
  };

  f32x4 acc[2][16] = {};
  stageA(0);
  stageB(0);
  for (int ct = 0; ct < 8; ++ct) {
    VMW(0);
    barrier_fenced();
    if (ct < 7) {
      stageA(ct + 1);
      stageB(ct + 1);
    }
    f16x8 af[2];
#pragma unroll
    for (int i = 0; i < 2; ++i) af[i] = ldA(ct, w32 + i * 16 + l15);
#pragma unroll
    for (int f = 0; f < 16; ++f) {
      f16x8 bf = ldB(ct, f * 16 + l15);
#pragma unroll
      for (int i = 0; i < 2; ++i)
        acc[i][f] = __builtin_amdgcn_mfma_f32_16x16x32_f16(af[i], bf, acc[i][f], 0, 0, 0);
    }
  }
#pragma unroll
  for (int i = 0; i < 2; ++i)
#pragma unroll
    for (int f = 0; f < 16; ++f)
#pragma unroll
      for (int jj = 0; jj < 4; ++jj)
        C[(w32 + i * 16 + lg * 4 + jj) * 256 + f * 16 + l15] = (f16)acc[i][f][jj];
}

// ---------------- vcomp: v[bc][h][j] = sum_c xb[bc][j][c] * wv[h][c] ----------------
__global__ __launch_bounds__(256) void vcomp(const f16* __restrict__ xb,
                                             const float* __restrict__ wv,
                                             float* __restrict__ v) {
  __shared__ float wl[2048];
  const int bc = blockIdx.x, tid = threadIdx.x;
  for (int r = 0; r < 8; ++r) wl[r * 256 + tid] = wv[r * 256 + tid];
  __syncthreads();
  const f16* row = xb + (long)bc * 65536 + (long)tid * 256;
  float a[8] = {};
  for (int c8 = 0; c8 < 32; ++c8) {
    f16x8 xv = *(const f16x8*)(row + c8 * 8);
#pragma unroll
    for (int h = 0; h < 8; ++h) {
      float s = 0.f;
#pragma unroll
      for (int e = 0; e < 8; ++e) s += (float)xv[e] * wl[h * 256 + c8 * 8 + e];
      a[h] += s;
    }
  }
  for (int h = 0; h < 8; ++h) v[bc * 2048 + h * 256 + tid] = a[h];
}

// ---------------- attn_fused7: 256-row blocks, 32x32x16 MFMA, continuous pipeline ----
// Block (bc, h): 256 q rows; 8 waves x 32 wave-private rows.
// One 64-step B-stream: phases T(MT) S(xB) R(xT) Z(GT), each 16 steps of
// [128 n][32 k] 8KB tiles through 4 rotating bufs, counted VMW(2) throughout.
// region0 @0: [256][256] f16 (xA staged -> T -> P -> R), swizzle
//   byte = row*512 + (col*2 ^ ((row&7)<<4)); rows wave-private: no barriers.
// B bufs @131072: 4 x 8KB. LDS = 160 KB exactly -> 1 block/CU.
// launch_bounds(512, 1): workgroup 512 => schedulability cap = 256 VGPR/wave
// (2 waves/SIMD x 256 = full pool). acc needs 128 AGPR; (512,2)'s 128-cap
// spilled ~100MB/dispatch (round-12 counters: WRITE 165MB, VGPR pinned at 128).
__global__ __launch_bounds__(512, 1) void attn_fused7(
    const f16* __restrict__ xb, const f16* __restrict__ xbT,
    const f16* __restrict__ MT, const f16* __restrict__ GT,
    const float* __restrict__ vw, f16* __restrict__ Zp) {
  __shared__ __align__(16) char smem[163840];
  const int tid = threadIdx.x;
  const int lane = tid & 63, wid = tid >> 6;  // 8 waves
  const int l31 = lane & 31, lh = lane >> 5;
  const int w32 = wid * 32;
  const int bc = blockIdx.x, h = blockIdx.y;
  const f16* xB = xb + (long)bc * 65536;   // [t][c] (also the phase-T A source)
  const f16* xT = xbT + (long)bc * 65536;  // [c][t]
  const f16* MTh = MT + h * 65536;         // [c'][c]
  const f16* GTh = GT + h * 65536;         // [dm][c]

  float vv[8];
  {
    const float* vb = vw + bc * 2048 + h * 256;
#pragma unroll
    for (int idx = 0; idx < 8; ++idx)
      vv[idx] = vb[(idx >> 2) * 128 + (idx & 3) * 32 + l31];
  }

  // stage full xA (=x_bc, 128KB) into region0 (linear dest, pre-swizzled src)
  auto stageX = [&]() {
#pragma unroll
    for (int i = 0; i < 16; ++i) {
      int flat = i * 8192 + tid * 16;
      int row = flat >> 9;
      int colb = (flat & 511) ^ ((row & 7) << 4);
      gload16(xB + (long)row * 256 + (colb >> 1), smem + flat);
    }
  };
  // stage B tile for global step g: 8KB, 1 load/thread
  auto stageBg = [&](int g) {
    const f16* src = g < 16 ? MTh : g < 32 ? xB : g < 48 ? xT : GTh;
    int s = g & 15, kt = s >> 1, hf = s & 1;
    int flat = tid * 16;
    int row = flat >> 6;  // 0..127
    int colb = (flat & 63) ^ (((row >> 1) & 3) << 4);
    gload16(src + (long)(hf * 128 + row) * 256 + kt * 32 + (colb >> 1),
            smem + 131072 + (g & 3) * 8192 + flat);
  };
  auto ldA = [&](int kt, int kf) -> f16x8 {
    int row = w32 + l31;
    return *(const f16x8*)(smem + row * 512 +
                           ((kt * 64 + kf * 32 + lh * 16) ^ ((row & 7) << 4)));
  };
  auto ldB = [&](int g, int nt, int kf) -> f16x8 {
    int row = nt * 32 + l31;
    return *(const f16x8*)(smem + 131072 + (g & 3) * 8192 + row * 64 +
                           ((kf * 32 + lh * 16) ^ (((row >> 1) & 3) << 4)));
  };
  auto st0 = [&](int row, int col, f16 v_) {
    *(f16*)(smem + row * 512 + ((col * 2) ^ ((row & 7) << 4))) = v_;
  };

  f32x16 acc[8];
  auto zacc = [&]() {
#pragma unroll
    for (int i = 0; i < 8; ++i) acc[i] = (f32x16)(0.f);
  };
  // one pipeline step; acc[hf*4+nt] over nt 0..3, kf 0..1 (g,kt,hf compile-time)
  auto step = [&](int g, int kt, int hf) {
    if (g < 62) {
      VMW(2);
    } else if (g == 62) {
      VMW(1);
    } else {
      VMW(0);
    }
    barrier_fenced();
    if (g + 3 < 64) stageBg(g + 3);
    f16x8 a0 = ldA(kt, 0), a1 = ldA(kt, 1);
    __builtin_amdgcn_s_setprio(1);
#pragma unroll
    for (int nt = 0; nt < 4; ++nt) {
      f16x8 b0 = ldB(g, nt, 0);
      acc[hf * 4 + nt] =
          __builtin_amdgcn_mfma_f32_32x32x16_f16(a0, b0, acc[hf * 4 + nt], 0, 0, 0);
      f16x8 b1 = ldB(g, nt, 1);
      acc[hf * 4 + nt] =
          __builtin_amdgcn_mfma_f32_32x32x16_f16(a1, b1, acc[hf * 4 + nt], 0, 0, 0);
    }
    __builtin_amdgcn_s_setprio(0);
  };
  // write acc to region0 (own rows; C layout row=(r&3)+8*(r>>2)+4*lh, col=lane&31)
  auto wr0 = [&]() {
#pragma unroll
    for (int idx = 0; idx < 8; ++idx)
#pragma unroll
      for (int r = 0; r < 16; ++r)
        st0(w32 + (r & 3) + 8 * (r >> 2) + 4 * lh,
            (idx >> 2) * 128 + (idx & 3) * 32 + l31, (f16)acc[idx][r]);
  };

  // prologue: xA + 3 B tiles in flight
  stageX();
  stageBg(0);
  stageBg(1);
  stageBg(2);

  // ---- phase T: T = xA * MT^T ----
  zacc();
#pragma unroll
  for (int s = 0; s < 16; ++s) step(s, s >> 1, s & 1);
  wr0();

  // ---- phase S: S = T * xB^T ----
  zacc();
#pragma unroll
  for (int s = 0; s < 16; ++s) step(16 + s, s >> 1, s & 1);

  // softmax over 256 j per row (rows wave-private; 32-lane groups per lh)
  {
    const float SCL = 0.0625f * 1.44269504089f;
#pragma unroll
    for (int r = 0; r < 16; ++r) {
      float m_ = acc[0][r] + vv[0];
#pragma unroll
      for (int idx = 1; idx < 8; ++idx) m_ = fmaxf(m_, acc[idx][r] + vv[idx]);
#pragma unroll
      for (int off = 1; off < 32; off <<= 1) m_ = fmaxf(m_, __shfl_xor(m_, off, 64));
      float s_ = 0.f;
#pragma unroll
      for (int idx = 0; idx < 8; ++idx) {
        float e = __builtin_exp2f((acc[idx][r] + vv[idx] - m_) * SCL);
        acc[idx][r] = e;
        s_ += e;
      }
#pragma unroll
      for (int off = 1; off < 32; off <<= 1) s_ += __shfl_xor(s_, off, 64);
      float inv = 1.f / s_;
#pragma unroll
      for (int idx = 0; idx < 8; ++idx) acc[idx][r] *= inv;
    }
  }
  wr0();  // P -> region0

  // ---- phase R: R = P * x (B = xT) ----
  zacc();
#pragma unroll
  for (int s = 0; s < 16; ++s) step(32 + s, s >> 1, s & 1);
  wr0();  // R -> region0

  // ---- phase Z: Z = R * G^T (B = GT) ----
  zacc();
#pragma unroll
  for (int s = 0; s < 16; ++s) step(48 + s, s >> 1, s & 1);

  // write Z partial: Zp[bc][t][h*256+dm]
  const long zb = (long)bc * 524288 + h * 256;
#pragma unroll
  for (int idx = 0; idx < 8; ++idx)
#pragma unroll
    for (int r = 0; r < 16; ++r) {
      int trow = w32 + (r & 3) + 8 * (r >> 2) + 4 * lh;
      int dm = (idx >> 2) * 128 + (idx & 3) * 32 + l31;
      Zp[zb + (long)trow * 2048 + dm] = (f16)acc[idx][r];
    }
}

// ---------------- reduce2: out = sum_h Zp + bo2 ----------------
__global__ __launch_bounds__(256) void reduce2(const f16* __restrict__ Zp,
                                               const float* __restrict__ bo2,
                                               float* __restrict__ out) {
  int g = blockIdx.x * 256 + threadIdx.x;  // 4096 blocks
  int flat = g * 4;                        // 4,194,304 f32 output
  int dm = flat & 255;
  int t = (flat >> 8) & 255;
  int bc = flat >> 16;  // 0..63
  const f16* zp = Zp + (long)bc * 524288 + (long)t * 2048 + dm;
  float4 s = *(const float4*)(bo2 + dm);
#pragma unroll
  for (int h = 0; h < 8; ++h) {
    f16x4 zv = *(const f16x4*)(zp + h * 256);
    s.x += (float)zv[0];
    s.y += (float)zv[1];
    s.z += (float)zv[2];
    s.w += (float)zv[3];
  }
  *(float4*)(out + flat) = s;
}

// ---------------- launch ----------------
// ws layout (bytes):
//   xb    @ 0         8388608    f16 [16384 tok][256 c]
//   xbT   @ 8388608   8388608    f16 [bc][256 c][256 t]
//   WqT2  @ 16777216  1048576    f16 [h*256+c][256 d]
//   WkT2  @ 17825792  1048576
//   WvT2  @ 18874368  1048576
//   WoT   @ 19922944  1048576    f16 [dm][h*256+d]
//   bqp   @ 20971520  8192       f32 [h*256+d]
//   bvp   @ 20979712  8192
//   MT    @ 20987904  1048576    f16 [h][c'][c]
//   GT    @ 22036480  1048576    f16 [h][dm][c]
//   wv    @ 23085056  8192       f32 [h][c]
//   bo2   @ 23093248  1024       f32 [dm]
//   v     @ 23094272  524288     f32 [bc][h][j]
//   Zp    @ 23618560  67108864   f16 [bc][t][h*256+dm]
extern "C" void kernel_launch(void* const* d_in, const int* in_sizes, int n_in,
                              void* d_out, int out_size, void* d_ws,
                              size_t ws_size, hipStream_t stream) {
  const float* x = (const float*)d_in[0];
  const float* Wq = (const float*)d_in[1];
  const float* bq = (const float*)d_in[2];
  const float* Wk = (const float*)d_in[3];
  const float* Wv = (const float*)d_in[5];
  const float* bv = (const float*)d_in[6];
  const float* Wo = (const float*)d_in[7];
  const float* bo = (const float*)d_in[8];

  char* ws = (char*)d_ws;
  f16* xb = (f16*)(ws + 0);
  f16* xbT = (f16*)(ws + 8388608);
  f16* WqT2 = (f16*)(ws + 16777216);
  f16* WkT2 = (f16*)(ws + 17825792);
  f16* WvT2 = (f16*)(ws + 18874368);
  f16* WoT = (f16*)(ws + 19922944);
  float* bqp = (float*)(ws + 20971520);
  float* bvp = (float*)(ws + 20979712);
  f16* MTws = (f16*)(ws + 20987904);
  f16* GTws = (f16*)(ws + 22036480);
  float* wvv = (float*)(ws + 23085056);
  float* bo2 = (float*)(ws + 23093248);
  float* vws = (float*)(ws + 23094272);
  f16* Zp = (f16*)(ws + 23618560);
  if (ws_size < 23618560ull + 67108864ull) return;  // ~87MB

  xpose<<<512, 256, 0, stream>>>(x, xb, xbT);
  prep_w2<<<2048, 256, 0, stream>>>(Wq, Wk, Wv, Wo, bq, bv, WqT2, WkT2, WvT2,
                                    WoT, bqp, bvp);
  gemm_pre<<<34, 256, 0, stream>>>(WqT2, WkT2, WvT2, WoT, bqp, bvp, bo, MTws,
                                   GTws, wvv, bo2);
  vcomp<<<64, 256, 0, stream>>>(xb, wvv, vws);
  // grid (bc, h): id = h*64+bc -> id%8 = bc%8: all 8 h-blocks of a bc on one XCD
  attn_fused7<<<dim3(64, 8), 512, 0, stream>>>(xb, xbT, MTws, GTws, vws, Zp);
  reduce2<<<4096, 256, 0, stream>>>(Zp, bo2, (float*)d_out);
}

// Round 14
// 220.185 us; speedup vs baseline: 1.0757x; 1.0600x over previous
//
#include <hip/hip_runtime.h>
#include <hip/hip_fp16.h>

typedef _Float16 f16;
typedef _Float16 f16x8 __attribute__((ext_vector_type(8)));
typedef _Float16 f16x4 __attribute__((ext_vector_type(4)));
typedef float f32x4 __attribute__((ext_vector_type(4)));
typedef float f32x16 __attribute__((ext_vector_type(16)));

#define GLB(p) ((const __attribute__((address_space(1))) void*)(p))
#define LDSP(p) ((__attribute__((address_space(3))) void*)(p))

__device__ __forceinline__ void gload16(const void* g, void* l) {
  __builtin_amdgcn_global_load_lds(GLB(g), LDSP(l), 16, 0, 0);
}

#define VMW(n) asm volatile("s_waitcnt vmcnt(" #n ")" ::: "memory")
__device__ __forceinline__ void barrier_fenced() {
  asm volatile("s_waitcnt lgkmcnt(0)" ::: "memory");
  __builtin_amdgcn_s_barrier();
  asm volatile("" ::: "memory");
}

// ---------------- xpose: x -> xb (f16 [t][c]) + xbT (f16 [bc][c][t]) ----------------
__global__ __launch_bounds__(256) void xpose(const float* __restrict__ x,
                                             f16* __restrict__ xb,
                                             f16* __restrict__ xbT) {
  __shared__ f16 t[32 * 268];
  const int tid = threadIdx.x;
  const int bc = blockIdx.x >> 3, tt = blockIdx.x & 7;
  const long tbase = (long)(bc * 256 + tt * 32);
#pragma unroll
  for (int i = 0; i < 8; ++i) {
    int tr = (tid >> 6) + i * 4;  // 0..31
    int c4 = (tid & 63) * 4;
    float4 v = *(const float4*)(x + (tbase + tr) * 256 + c4);
    f16x4 o = {(f16)v.x, (f16)v.y, (f16)v.z, (f16)v.w};
    *(f16x4*)(xb + (tbase + tr) * 256 + c4) = o;
    *(f16x4*)(&t[tr * 268 + c4]) = o;
  }
  __syncthreads();
#pragma unroll
  for (int i = 0; i < 8; ++i) {
    int c = (tid >> 3) + i * 32;  // 0..255
    int t0 = (tid & 7) * 4;       // 0..28
    f16x4 v;
#pragma unroll
    for (int j = 0; j < 4; ++j) v[j] = t[(t0 + j) * 268 + c];
    *(f16x4*)(&xbT[(long)bc * 65536 + (long)c * 256 + tt * 32 + t0]) = v;
  }
}

// ---------------- prep_w2: per-head K-innermost weights + permuted biases ----------
__global__ __launch_bounds__(256) void prep_w2(
    const float* __restrict__ Wq, const float* __restrict__ Wk,
    const float* __restrict__ Wv, const float* __restrict__ Wo,
    const float* __restrict__ bq, const float* __restrict__ bv,
    f16* __restrict__ WqT2, f16* __restrict__ WkT2, f16* __restrict__ WvT2,
    f16* __restrict__ WoT, float* __restrict__ bqp, float* __restrict__ bvp) {
  int g = blockIdx.x * 256 + threadIdx.x;  // 0..524287
  int hc = g >> 8, d = g & 255;
  int h = hc >> 8, c = hc & 255;
  int src = c * 2048 + d * 8 + h;
  WqT2[g] = (f16)Wq[src];
  WkT2[g] = (f16)Wk[src];
  WvT2[g] = (f16)Wv[src];
  int dm = g >> 11, np = g & 2047;
  WoT[g] = (f16)Wo[((np & 255) * 8 + (np >> 8)) * 256 + dm];
  if (g < 2048) {
    int s2 = (g & 255) * 8 + (g >> 8);
    bqp[g] = bq[s2];
    bvp[g] = bv[s2];
  }
}

// ---------------- gemm_pre: MT_h, GT_h (128x256 tiles, K=256) + wv + bo2 ----------
__global__ __launch_bounds__(256) void gemm_pre(
    const f16* __restrict__ WqT2, const f16* __restrict__ WkT2,
    const f16* __restrict__ WvT2, const f16* __restrict__ WoT,
    const float* __restrict__ bqp, const float* __restrict__ bvp,
    const float* __restrict__ bo, f16* __restrict__ MT, f16* __restrict__ GT,
    float* __restrict__ wv, float* __restrict__ bo2) {
  const int bid = blockIdx.x;
  if (bid >= 32) {
    if (bid == 32) {
      int c = threadIdx.x;
      for (int h = 0; h < 8; ++h) {
        const f16* row = WkT2 + ((h * 256 + c) << 8);
        float acc = 0.f;
        for (int d8 = 0; d8 < 32; ++d8) {
          f16x8 kv = *(const f16x8*)(row + d8 * 8);
#pragma unroll
          for (int e = 0; e < 8; ++e)
            acc += (float)kv[e] * bqp[h * 256 + d8 * 8 + e];
        }
        wv[h * 256 + c] = acc;
      }
    } else {
      int dm = threadIdx.x;
      const f16* row = WoT + dm * 2048;
      float acc = bo[dm];
      for (int n8 = 0; n8 < 256; ++n8) {
        f16x8 ov = *(const f16x8*)(row + n8 * 8);
#pragma unroll
        for (int e = 0; e < 8; ++e) acc += (float)ov[e] * bvp[n8 * 8 + e];
      }
      bo2[dm] = acc;
    }
    return;
  }
  __shared__ __align__(16) char smem[49152];  // A 2x8KB @0, B 2x16KB @16384
  const int mat = bid >> 4, h = (bid >> 1) & 7, mt = bid & 1;
  const f16* A;
  long As;
  const f16* B;
  f16* C;
  if (mat == 0) {
    A = WkT2 + h * 65536 + mt * 32768;
    As = 256;
    B = WqT2 + h * 65536;
    C = MT + h * 65536 + mt * 32768;
  } else {
    A = WoT + h * 256 + (long)mt * 128 * 2048;
    As = 2048;
    B = WvT2 + h * 65536;
    C = GT + h * 65536 + mt * 32768;
  }
  const int tid = threadIdx.x;
  const int lane = tid & 63, wid = tid >> 6;  // 4 waves
  const int l15 = lane & 15, lg = lane >> 4;
  const int w32 = wid * 32;

  auto stageA = [&](int ct) {
#pragma unroll
    for (int r = 0; r < 2; ++r) {
      int flat = r * 4096 + tid * 16;
      int row = flat >> 6;
      int kk = ct * 32 + (((flat ^ (((row >> 1) & 3) << 4)) & 63) >> 1);
      gload16(A + (long)row * As + kk, smem + (ct & 1) * 8192 + flat);
    }
  };
  auto stageB = [&](int ct) {
#pragma unroll
    for (int r = 0; r < 4; ++r) {
      int flat = r * 4096 + tid * 16;
      int row = flat >> 6;
      int kk = ct * 32 + (((flat ^ (((row >> 1) & 3) << 4)) & 63) >> 1);
      gload16(B + (long)row * 256 + kk, smem + 16384 + (ct & 1) * 16384 + flat);
    }
  };
  auto ldA = [&](int ct, int row) -> f16x8 {
    return *(const f16x8*)(smem + (ct & 1) * 8192 + row * 64 +
                           ((lg * 16) ^ (((row >> 1) & 3) << 4)));
  };
  auto ldB = [&](int ct, int row) -> f16x8 {
    return *(const f16x8*)(smem + 16384 + (ct & 1) * 16384 + row * 64 +
                           ((lg * 16) ^ (((row >> 1) & 3) << 4)));
  };

  f32x4 acc[2][16] = {};
  stageA(0);
  stageB(0);
  for (int ct = 0; ct < 8; ++ct) {
    VMW(0);
    barrier_fenced();
    if (ct < 7) {
      stageA(ct + 1);
      stageB(ct + 1);
    }
    f16x8 af[2];
#pragma unroll
    for (int i = 0; i < 2; ++i) af[i] = ldA(ct, w32 + i * 16 + l15);
#pragma unroll
    for (int f = 0; f < 16; ++f) {
      f16x8 bf = ldB(ct, f * 16 + l15);
#pragma unroll
      for (int i = 0; i < 2; ++i)
        acc[i][f] = __builtin_amdgcn_mfma_f32_16x16x32_f16(af[i], bf, acc[i][f], 0, 0, 0);
    }
  }
#pragma unroll
  for (int i = 0; i < 2; ++i)
#pragma unroll
    for (int f = 0; f < 16; ++f)
#pragma unroll
      for (int jj = 0; jj < 4; ++jj)
        C[(w32 + i * 16 + lg * 4 + jj) * 256 + f * 16 + l15] = (f16)acc[i][f][jj];
}

// ---------------- vcomp: v[bc][h][j] = sum_c xb[bc][j][c] * wv[h][c] ----------------
__global__ __launch_bounds__(256) void vcomp(const f16* __restrict__ xb,
                                             const float* __restrict__ wv,
                                             float* __restrict__ v) {
  __shared__ float wl[2048];
  const int bc = blockIdx.x, tid = threadIdx.x;
  for (int r = 0; r < 8; ++r) wl[r * 256 + tid] = wv[r * 256 + tid];
  __syncthreads();
  const f16* row = xb + (long)bc * 65536 + (long)tid * 256;
  float a[8] = {};
  for (int c8 = 0; c8 < 32; ++c8) {
    f16x8 xv = *(const f16x8*)(row + c8 * 8);
#pragma unroll
    for (int h = 0; h < 8; ++h) {
      float s = 0.f;
#pragma unroll
      for (int e = 0; e < 8; ++e) s += (float)xv[e] * wl[h * 256 + c8 * 8 + e];
      a[h] += s;
    }
  }
  for (int h = 0; h < 8; ++h) v[bc * 2048 + h * 256 + tid] = a[h];
}

// ---------------- attn_fused8: 128-row blocks, 32x32x16, acc=64 (no spill) ----------
// Block (bc, qt, h): 128 q rows. 8 waves = 4 row-groups x 2 col-halves;
// per-wave output 32 rows x 128 cols -> acc 4 x f32x16 = 64 regs.
// LDS 160KB: region0 @0 = xA [128][512B] (dead after phase T -> softmax stats);
//   region1 @65536 = T -> P -> R [128][512B]; B @131072 = 4 x 8KB granules.
// 64-granule B stream (MT,xB,xT,GT), 2 granules (both col-halves) per k-step;
// 32 global steps, each: VMW(0), barrier, stage next pair, 2 A + 8 B reads,
// 8 MFMA(32x32x16). Cross-half softmax via 2-pass stats in dead region0.
__global__ __launch_bounds__(512, 2) void attn_fused8(
    const f16* __restrict__ xb, const f16* __restrict__ xbT,
    const f16* __restrict__ MT, const f16* __restrict__ GT,
    const float* __restrict__ vw, f16* __restrict__ Zp) {
  __shared__ __align__(16) char smem[163840];
  const int tid = threadIdx.x;
  const int lane = tid & 63, wid = tid >> 6;
  const int l31 = lane & 31, lh = lane >> 5;
  const int rw = (wid & 3) * 32;  // wave's 32 rows
  const int ch = wid >> 2;        // col half
  const int bc = blockIdx.x, qt = blockIdx.y, h = blockIdx.z;
  const f16* xB = xb + (long)bc * 65536;   // [t][c]
  const f16* xA = xB + (long)qt * 32768;   // this block's 128 rows
  const f16* xT = xbT + (long)bc * 65536;  // [c][t]
  const f16* MTh = MT + h * 65536;
  const f16* GTh = GT + h * 65536;

  float vv[4];
#pragma unroll
  for (int nt = 0; nt < 4; ++nt)
    vv[nt] = vw[bc * 2048 + h * 256 + ch * 128 + nt * 32 + l31];

  // xA -> region0, linear dest, pre-swizzled source (byte = row*512 + cb,
  // holds x[row][((cb^(row&31)<<4)>>1)])
  auto stageX = [&]() {
#pragma unroll
    for (int i = 0; i < 8; ++i) {
      int flat = i * 8192 + tid * 16;
      int row = flat >> 9;
      int cb = (flat & 511) ^ ((row & 31) << 4);
      gload16(xA + (long)row * 256 + (cb >> 1), smem + flat);
    }
  };
  // B granule g (0..63): [128 n][32 k] 8KB, src row hf*128+row, k kt*32..
  auto stageG = [&](int g) {
    const f16* src = g < 16 ? MTh : g < 32 ? xB : g < 48 ? xT : GTh;
    int s = g & 15, kt = s >> 1, hf = s & 1;
    int flat = tid * 16;
    int row = flat >> 6;
    int cb = (flat & 63) ^ (((row >> 1) & 3) << 4);
    gload16(src + (long)(hf * 128 + row) * 256 + kt * 32 + (cb >> 1),
            smem + 131072 + (g & 3) * 8192 + flat);
  };
  auto ldA = [&](int regbase, int kt, int kf) -> f16x8 {
    int row = rw + l31;
    return *(const f16x8*)(smem + regbase + row * 512 +
                           ((kt * 64 + kf * 32 + lh * 16) ^ ((row & 31) << 4)));
  };
  auto ldB = [&](int t, int nt, int kf) -> f16x8 {
    int rl = nt * 32 + l31;
    return *(const f16x8*)(smem + 131072 + ((2 * t + ch) & 3) * 8192 + rl * 64 +
                           ((kf * 32 + lh * 16) ^ (((rl >> 1) & 3) << 4)));
  };
  auto st1 = [&](int row, int col, f16 v_) {
    *(f16*)(smem + 65536 + row * 512 + ((col * 2) ^ ((row & 31) << 4))) = v_;
  };

  f32x16 acc[4];
  auto zacc = [&]() {
#pragma unroll
    for (int i = 0; i < 4; ++i) acc[i] = (f32x16)(0.f);
  };
  auto step = [&](int t, int abase) {
    VMW(0);            // this step's granule pair landed (issued last step)
    barrier_fenced();  // visible to all waves; prev-step bufs free
    if (t < 31) {
      stageG(2 * t + 2);
      stageG(2 * t + 3);
    }
    const int kt = t & 7;
    f16x8 a0 = ldA(abase, kt, 0), a1 = ldA(abase, kt, 1);
    __builtin_amdgcn_s_setprio(1);
#pragma unroll
    for (int nt = 0; nt < 4; ++nt) {
      f16x8 b0 = ldB(t, nt, 0);
      acc[nt] = __builtin_amdgcn_mfma_f32_32x32x16_f16(a0, b0, acc[nt], 0, 0, 0);
      f16x8 b1 = ldB(t, nt, 1);
      acc[nt] = __builtin_amdgcn_mfma_f32_32x32x16_f16(a1, b1, acc[nt], 0, 0, 0);
    }
    __builtin_amdgcn_s_setprio(0);
  };
  // write acc to region1 (own rows; C layout row=(r&3)+8*(r>>2)+4*lh, col=l31)
  auto wr1 = [&]() {
#pragma unroll
    for (int nt = 0; nt < 4; ++nt)
#pragma unroll
      for (int r = 0; r < 16; ++r)
        st1(rw + (r & 3) + 8 * (r >> 2) + 4 * lh, ch * 128 + nt * 32 + l31,
            (f16)acc[nt][r]);
  };

  // prologue
  stageX();
  stageG(0);
  stageG(1);

  // ---- phase T: T = xA * MT^T (A = region0) ----
  zacc();
#pragma unroll
  for (int s = 0; s < 8; ++s) step(s, 0);
  wr1();  // T -> region1 (A was region0: no overwrite hazard)

  // ---- phase S: S = T * xB^T (A = region1) ----
  zacc();
#pragma unroll
  for (int s = 0; s < 8; ++s) step(8 + s, 65536);

  // ---- softmax across col-halves (stats in dead region0) ----
  {
    float* mbuf = (float*)smem;           // [2][128]
    float* lbuf = (float*)(smem + 1024);  // [2][128]
    const float SCL = 0.0625f * 1.44269504089f;
    float m_[16], ps[16];
#pragma unroll
    for (int r = 0; r < 16; ++r) {
      int row = rw + (r & 3) + 8 * (r >> 2) + 4 * lh;
      float pm = acc[0][r] + vv[0];
#pragma unroll
      for (int nt = 1; nt < 4; ++nt) pm = fmaxf(pm, acc[nt][r] + vv[nt]);
#pragma unroll
      for (int off = 1; off < 32; off <<= 1) pm = fmaxf(pm, __shfl_xor(pm, off, 64));
      m_[r] = pm;
      if (l31 == 0) mbuf[ch * 128 + row] = pm;
    }
    barrier_fenced();  // also: all S-phase A-reads of region1 complete
#pragma unroll
    for (int r = 0; r < 16; ++r) {
      int row = rw + (r & 3) + 8 * (r >> 2) + 4 * lh;
      float m = fmaxf(m_[r], mbuf[(1 - ch) * 128 + row]);
      m_[r] = m;
      float s_ = 0.f;
#pragma unroll
      for (int nt = 0; nt < 4; ++nt) {
        float e = __builtin_exp2f((acc[nt][r] + vv[nt] - m) * SCL);
        acc[nt][r] = e;
        s_ += e;
      }
#pragma unroll
      for (int off = 1; off < 32; off <<= 1) s_ += __shfl_xor(s_, off, 64);
      ps[r] = s_;
      if (l31 == 0) lbuf[ch * 128 + row] = s_;
    }
    barrier_fenced();
#pragma unroll
    for (int r = 0; r < 16; ++r) {
      int row = rw + (r & 3) + 8 * (r >> 2) + 4 * lh;
      float inv = 1.f / (ps[r] + lbuf[(1 - ch) * 128 + row]);
#pragma unroll
      for (int nt = 0; nt < 4; ++nt) acc[nt][r] *= inv;
    }
  }
  wr1();  // P -> region1 (all T-reads finished at softmax barrier 1)

  // ---- phase R: R = P * x (A = region1, B = xT) ----
  zacc();
#pragma unroll
  for (int s = 0; s < 8; ++s) step(16 + s, 65536);
  barrier_fenced();  // all waves' P-reads done before R overwrites region1
  wr1();             // R -> region1

  // ---- phase Z: Z = R * GT^T (A = region1) ----
  zacc();
#pragma unroll
  for (int s = 0; s < 8; ++s) step(24 + s, 65536);

  // write Z partial: Zp[bc][t][h*256+dm]
  const long zb = (long)bc * 524288 + (long)(qt * 128) * 2048 + h * 256;
#pragma unroll
  for (int nt = 0; nt < 4; ++nt)
#pragma unroll
    for (int r = 0; r < 16; ++r) {
      int trow = rw + (r & 3) + 8 * (r >> 2) + 4 * lh;
      int dm = ch * 128 + nt * 32 + l31;
      Zp[zb + (long)trow * 2048 + dm] = (f16)acc[nt][r];
    }
}

// ---------------- reduce2: out = sum_h Zp + bo2 ----------------
__global__ __launch_bounds__(256) void reduce2(const f16* __restrict__ Zp,
                                               const float* __restrict__ bo2,
                                               float* __restrict__ out) {
  int g = blockIdx.x * 256 + threadIdx.x;  // 4096 blocks
  int flat = g * 4;                        // 4,194,304 f32 output
  int dm = flat & 255;
  int t = (flat >> 8) & 255;
  int bc = flat >> 16;  // 0..63
  const f16* zp = Zp + (long)bc * 524288 + (long)t * 2048 + dm;
  float4 s = *(const float4*)(bo2 + dm);
#pragma unroll
  for (int h = 0; h < 8; ++h) {
    f16x4 zv = *(const f16x4*)(zp + h * 256);
    s.x += (float)zv[0];
    s.y += (float)zv[1];
    s.z += (float)zv[2];
    s.w += (float)zv[3];
  }
  *(float4*)(out + flat) = s;
}

// ---------------- launch ----------------
// ws layout (bytes):
//   xb    @ 0         8388608    f16 [16384 tok][256 c]
//   xbT   @ 8388608   8388608    f16 [bc][256 c][256 t]
//   WqT2  @ 16777216  1048576    f16 [h*256+c][256 d]
//   WkT2  @ 17825792  1048576
//   WvT2  @ 18874368  1048576
//   WoT   @ 19922944  1048576    f16 [dm][h*256+d]
//   bqp   @ 20971520  8192       f32 [h*256+d]
//   bvp   @ 20979712  8192
//   MT    @ 20987904  1048576    f16 [h][c'][c]
//   GT    @ 22036480  1048576    f16 [h][dm][c]
//   wv    @ 23085056  8192       f32 [h][c]
//   bo2   @ 23093248  1024       f32 [dm]
//   v     @ 23094272  524288     f32 [bc][h][j]
//   Zp    @ 23618560  67108864   f16 [bc][t][h*256+dm]
extern "C" void kernel_launch(void* const* d_in, const int* in_sizes, int n_in,
                              void* d_out, int out_size, void* d_ws,
                              size_t ws_size, hipStream_t stream) {
  const float* x = (const float*)d_in[0];
  const float* Wq = (const float*)d_in[1];
  const float* bq = (const float*)d_in[2];
  const float* Wk = (const float*)d_in[3];
  const float* Wv = (const float*)d_in[5];
  const float* bv = (const float*)d_in[6];
  const float* Wo = (const float*)d_in[7];
  const float* bo = (const float*)d_in[8];

  char* ws = (char*)d_ws;
  f16* xb = (f16*)(ws + 0);
  f16* xbT = (f16*)(ws + 8388608);
  f16* WqT2 = (f16*)(ws + 16777216);
  f16* WkT2 = (f16*)(ws + 17825792);
  f16* WvT2 = (f16*)(ws + 18874368);
  f16* WoT = (f16*)(ws + 19922944);
  float* bqp = (float*)(ws + 20971520);
  float* bvp = (float*)(ws + 20979712);
  f16* MTws = (f16*)(ws + 20987904);
  f16* GTws = (f16*)(ws + 22036480);
  float* wvv = (float*)(ws + 23085056);
  float* bo2 = (float*)(ws + 23093248);
  float* vws = (float*)(ws + 23094272);
  f16* Zp = (f16*)(ws + 23618560);
  if (ws_size < 23618560ull + 67108864ull) return;  // ~87MB

  xpose<<<512, 256, 0, stream>>>(x, xb, xbT);
  prep_w2<<<2048, 256, 0, stream>>>(Wq, Wk, Wv, Wo, bq, bv, WqT2, WkT2, WvT2,
                                    WoT, bqp, bvp);
  gemm_pre<<<34, 256, 0, stream>>>(WqT2, WkT2, WvT2, WoT, bqp, bvp, bo, MTws,
                                   GTws, wvv, bo2);
  vcomp<<<64, 256, 0, stream>>>(xb, wvv, vws);
  // grid (bc, qt, h): linear id = bc + 64*qt + 128*h -> id%8 = bc%8:
  // all 16 blocks of a bc land on one XCD (xb/xbT slice L2-resident)
  attn_fused8<<<dim3(64, 2, 8), 512, 0, stream>>>(xb, xbT, MTws, GTws, vws, Zp);
  reduce2<<<4096, 256, 0, stream>>>(Zp, bo2, (float*)d_out);
}